// Round 9
// baseline (162.868 us; speedup 1.0000x reference)
//
#include <hip/hip_runtime.h>
#include <hip/hip_bf16.h>
#include <stdint.h>

#define NN 10000
#define NE 320000
#define NH 4
#define BCAP 128                     // per-node bucket capacity (max deg ~60 for this graph)

#define GEMM1_MT 157                 // ceil(10000/64) 64-row tiles per head
#define GEMM1_BLOCKS (GEMM1_MT * 4)
#define BUILD_BLOCKS 1250            // ceil(320000/256)

typedef __attribute__((ext_vector_type(8))) short s16x8;
typedef __attribute__((ext_vector_type(4))) float f32x4;
typedef __attribute__((ext_vector_type(8))) unsigned short u16x8;

static __device__ __forceinline__ float b2f(unsigned short u) {
    union { unsigned int i; float f; } x; x.i = ((unsigned int)u) << 16; return x.f;
}
static __device__ __forceinline__ unsigned short f2b(float f) {
    unsigned int u = __float_as_uint(f);
    unsigned int r = (u + 0x7fffu + ((u >> 16) & 1u)) >> 16;
    return (unsigned short)r;
}

// dtype detect: block-local, deterministic (2048 samples, >20 sigma margin)
static __device__ __forceinline__ int detect_isbf(const unsigned short* hraw, int t, int* sb) {
    int c = 0;
    for (int i = t; i < 2048; i += 256) {
        unsigned short u = hraw[i];
        int e = (u >> 7) & 0xFF;
        c += (e >= 97 && e <= 157) ? 1 : 0;     // |x| in [2^-30, 2^30]
    }
    sb[t] = c;
    __syncthreads();
    for (int o = 128; o > 0; o >>= 1) {
        if (t < o) sb[t] += sb[t + o];
        __syncthreads();
    }
    return (sb[0] >= 1741) ? 1 : 0;             // 85% of 2048
}

// inline small-tensor conversion: same value chain as the old canon path
// (isbf ? raw : f2b(raw)) read back through b2f -> bit-identical floats.
static __device__ __forceinline__ float ld_param(const void* p, int idx, int isbf) {
    return isbf ? b2f(((const unsigned short*)p)[idx])
                : b2f(f2b(((const float*)p)[idx]));
}

// ---------------- B-tile transpose-stage straight from raw W (replaces prep's W^T) -----
// Bs[n][k] = conv(W[k][col0+n]), n in [0,64), k in [0,256). Reads are 16B chunks over
// contiguous 128B row-slices (coalesced); conversion identical to old prep (same f2b)
// -> identical LDS contents -> identical MFMA inputs.
#define BSTRIDE 264   // shorts; 528B row: 16B-aligned, bank rotation 4r mod 32
static __device__ __forceinline__ void stage_bt(short* Bs, const void* W, int wcols,
                                                int col0, int isbf, int t) {
    int kk = t >> 3, nc = t & 7;
#pragma unroll
    for (int i = 0; i < 8; ++i) {
        int k = i * 32 + kk;
        short v[8];
        if (isbf) {
            s16x8 x = *(const s16x8*)((const unsigned short*)W + (size_t)k * wcols + col0 + nc * 8);
#pragma unroll
            for (int j = 0; j < 8; ++j) v[j] = x[j];
        } else {
            const float* pf = (const float*)W + (size_t)k * wcols + col0 + nc * 8;
            float4 x0 = *(const float4*)pf;
            float4 x1 = *(const float4*)(pf + 4);
            v[0] = (short)f2b(x0.x); v[1] = (short)f2b(x0.y);
            v[2] = (short)f2b(x0.z); v[3] = (short)f2b(x0.w);
            v[4] = (short)f2b(x1.x); v[5] = (short)f2b(x1.y);
            v[6] = (short)f2b(x1.z); v[7] = (short)f2b(x1.w);
        }
#pragma unroll
        for (int j = 0; j < 8; ++j) Bs[(nc * 8 + j) * BSTRIDE + k] = v[j];
    }
}

// ---------------- GEMM core: 64 rows x one head's 64 cols from pre-staged Bs -----------
static __device__ __forceinline__ void gemm_core(const short* Bs,
                        const void* __restrict__ A, unsigned short* __restrict__ C,
                        float* __restrict__ el, float* __restrict__ er,
                        const void* al_raw, const void* ar_raw, int p_isbf,
                        int M, int N, int H, int a_isbf, int mtile, int head) {
    int t = threadIdx.x;
    int wave = t >> 6, lane = t & 63;
    int m0 = mtile * 64;

    int kq = (lane >> 4) * 8;
    const unsigned short* Ab = (const unsigned short*)A;
    const float*          Af = (const float*)A;
    int aRow = m0 + wave * 16 + (lane & 15);
    int aR = (aRow < M) ? aRow : M - 1;          // clamp loads; stores guarded
    f32x4 acc[4] = {};

#pragma unroll
    for (int k0 = 0; k0 < 256; k0 += 32) {
        s16x8 afr;
        if (a_isbf) {
            afr = *(const s16x8*)&Ab[(size_t)aR * 256 + k0 + kq];
        } else {
            const float* pf = &Af[(size_t)aR * 256 + k0 + kq];
            float4 x0 = *(const float4*)pf;
            float4 x1 = *(const float4*)(pf + 4);
            afr[0] = (short)f2b(x0.x); afr[1] = (short)f2b(x0.y);
            afr[2] = (short)f2b(x0.z); afr[3] = (short)f2b(x0.w);
            afr[4] = (short)f2b(x1.x); afr[5] = (short)f2b(x1.y);
            afr[6] = (short)f2b(x1.z); afr[7] = (short)f2b(x1.w);
        }
#pragma unroll
        for (int nt = 0; nt < 4; ++nt) {
            s16x8 bfr = *(const s16x8*)&Bs[(nt * 16 + (lane & 15)) * BSTRIDE + k0 + kq];
            acc[nt] = __builtin_amdgcn_mfma_f32_16x16x32_bf16(afr, bfr, acc[nt], 0, 0, 0);
        }
    }

    float alv[4], arv[4];
#pragma unroll
    for (int nt = 0; nt < 4; ++nt) {
        int c = (lane & 15) + nt * 16;
        alv[nt] = ld_param(al_raw, head * 64 + c, p_isbf);
        arv[nt] = ld_param(ar_raw, head * 64 + c, p_isbf);
    }
    int col0 = head * 64 + (lane & 15);
    int r0 = m0 + wave * 16 + (lane >> 4) * 4;
    float cr[4][4];
#pragma unroll
    for (int nt = 0; nt < 4; ++nt) {
        int col = col0 + nt * 16;
#pragma unroll
        for (int i = 0; i < 4; ++i) {
            unsigned short cb = f2b(acc[nt][i]);
            cr[nt][i] = b2f(cb);
            int r = r0 + i;
            if (r < M) C[(size_t)r * N + col] = cb;
        }
    }
#pragma unroll
    for (int i = 0; i < 4; ++i) {
        float pl = 0.f, pr = 0.f;
#pragma unroll
        for (int nt = 0; nt < 4; ++nt) {
            pl += cr[nt][i] * alv[nt];
            pr += cr[nt][i] * arv[nt];
        }
#pragma unroll
        for (int o = 1; o < 16; o <<= 1) {
            pl += __shfl_xor(pl, o, 64);
            pr += __shfl_xor(pr, o, 64);
        }
        int r = r0 + i;
        if ((lane & 15) == 0 && r < M) {
            el[(size_t)r * H + head] = pl;
            er[(size_t)r * H + head] = pr;
        }
    }
}

// ---------------- fused: layer-1 GEMM (self-contained) + bucket CSR build --------------
// GEMM blocks: local isbf detect + inline W1 transpose-stage + inline al1/ar1 -> no k_prep
// dependency. Block 0 publishes flag for downstream kernels. Bucket half needs only the
// memset'd cnt. This deletes the prep dispatch + its gap from the serial chain.
__global__ __launch_bounds__(256) void k_g1b(const void* __restrict__ A,
                        const void* __restrict__ W1,
                        unsigned short* __restrict__ feat1,
                        float* __restrict__ el, float* __restrict__ er,
                        const void* __restrict__ al1, const void* __restrict__ ar1,
                        const int* __restrict__ src, const int* __restrict__ dst,
                        int* __restrict__ cnt, int* __restrict__ bucket,
                        int* __restrict__ flag) {
    __shared__ short Bs[64 * BSTRIDE];
    __shared__ int sb[256];
    int bid = blockIdx.x;
    int t = threadIdx.x;
    if (bid < GEMM1_BLOCKS) {
        int isbf = detect_isbf((const unsigned short*)A, t, sb);
        if (bid == 0 && t == 0) flag[0] = isbf;
        int head = bid / GEMM1_MT;
        int mtile = bid - head * GEMM1_MT;
        stage_bt(Bs, W1, 256, head * 64, isbf, t);
        __syncthreads();
        gemm_core(Bs, A, feat1, el, er, al1, ar1, isbf, NN, 256, NH, isbf, mtile, head);
    } else {
        int i = (bid - GEMM1_BLOCKS) * 256 + t;
        if (i < NE) {
            int d = dst[i];
            int pos = atomicAdd(&cnt[d], 1);
            if (pos < BCAP) bucket[(d << 7) + pos] = src[i];   // cap unreachable: max deg ~60
        }
    }
}

// ---------------- layer-1 edges: HEAD-SLICED wave per (node, head) ---------------------
// Head-major grid: concurrently-resident blocks gather from ONE head's 1.28MB feat1 slab
// -> L2-resident (r8: -4.2us vs interleaved heads). b1 converted inline via flag.
__global__ __launch_bounds__(256, 8) void k_e1h(const int* __restrict__ cnt,
                        const int* __restrict__ bucket,
                        const float* __restrict__ el, const float* __restrict__ er,
                        const unsigned short* __restrict__ feat,
                        const void* __restrict__ b1,
                        const int* __restrict__ flagp,
                        unsigned short* __restrict__ h1) {
    int wave = threadIdx.x >> 6, lane = threadIdx.x & 63;
    int bid = blockIdx.x;
    int head = bid / 2500;                        // head-major: locality window = 1 slab
    int node = (bid - head * 2500) * 4 + wave;    // 2500*4 == 10000 exactly
    int eg = lane >> 3, d8 = lane & 7;
    int isbf = flagp[0];
    int end = cnt[node]; if (end > BCAP) end = BCAP;
    const int* bkt = bucket + ((size_t)node << 7);
    float er_d = er[(size_t)node * 4 + head];

    if (end <= 64) {                              // fast path: one edge per lane
        int s = 0; float w = 0.f;
        if (lane < end) {
            s = bkt[lane];
            float x = el[(size_t)s * 4 + head] + er_d;
            x = (x >= 0.f) ? x : 0.2f * x;
            w = __expf(x);                        // |x| ~ O(1): shift-free softmax
        }
        float ls = w;
#pragma unroll
        for (int o = 1; o < 64; o <<= 1) ls += __shfl_xor(ls, o, 64);
        float a[8] = {};
        int niter = (end + 7) >> 3;
#pragma unroll 4
        for (int i = 0; i < niter; ++i) {
            int idx = 8 * i + eg;
            int   se = __shfl(s, idx, 64);
            float we = __shfl(w, idx, 64);
            u16x8 fv = *(const u16x8*)&feat[(((size_t)se * NH + head) << 6) + (d8 << 3)];
#pragma unroll
            for (int j = 0; j < 8; ++j) a[j] += we * b2f(fv[j]);
        }
#pragma unroll
        for (int j = 0; j < 8; ++j) {
            a[j] += __shfl_xor(a[j], 8, 64);
            a[j] += __shfl_xor(a[j], 16, 64);
            a[j] += __shfl_xor(a[j], 32, 64);
        }
        if (eg == 0) {
            float inv = (ls > 0.f) ? 1.f / ls : 0.f;
            u16x8 r;
#pragma unroll
            for (int j = 0; j < 8; ++j) {
                float o = a[j] * inv + ld_param(b1, head * 64 + d8 * 8 + j, isbf);
                o = (o > 0.f) ? o : (__expf(o) - 1.f);   // ELU
                r[j] = f2b(o);
            }
            *(u16x8*)&h1[(((size_t)node * NH + head) << 6) + d8 * 8] = r;
        }
    } else {                                      // slow path: chunked (deg > 64; unused here)
        float a[8] = {};
        float ls = 0.f;
        for (int base = 0; base < end; base += 64) {
            int c = base + lane;
            int s = 0; float w = 0.f;
            if (c < end) {
                s = bkt[c];
                float x = el[(size_t)s * 4 + head] + er_d;
                x = (x >= 0.f) ? x : 0.2f * x;
                w = __expf(x);
            }
            ls += w;
            int cn = end - base; if (cn > 64) cn = 64;
            int niter = (cn + 7) >> 3;
#pragma unroll 2
            for (int i = 0; i < niter; ++i) {
                int idx = 8 * i + eg;
                int   se = __shfl(s, idx, 64);
                float we = __shfl(w, idx, 64);
                u16x8 fv = *(const u16x8*)&feat[(((size_t)se * NH + head) << 6) + (d8 << 3)];
#pragma unroll
                for (int j = 0; j < 8; ++j) a[j] += we * b2f(fv[j]);
            }
        }
#pragma unroll
        for (int o = 1; o < 64; o <<= 1) ls += __shfl_xor(ls, o, 64);
#pragma unroll
        for (int j = 0; j < 8; ++j) {
            a[j] += __shfl_xor(a[j], 8, 64);
            a[j] += __shfl_xor(a[j], 16, 64);
            a[j] += __shfl_xor(a[j], 32, 64);
        }
        if (eg == 0) {
            float inv = (ls > 0.f) ? 1.f / ls : 0.f;
            u16x8 r;
#pragma unroll
            for (int j = 0; j < 8; ++j) {
                float o = a[j] * inv + ld_param(b1, head * 64 + d8 * 8 + j, isbf);
                o = (o > 0.f) ? o : (__expf(o) - 1.f);
                r[j] = f2b(o);
            }
            *(u16x8*)&h1[(((size_t)node * NH + head) << 6) + d8 * 8] = r;
        }
    }
}

// ---------------- standalone GEMM for layer 2 (A=h1 bf16; W2 staged inline) ------------
__global__ __launch_bounds__(256) void k_gemm(const void* __restrict__ A,
                                              const void* __restrict__ W2,
                                              unsigned short* __restrict__ C,
                                              float* __restrict__ el, float* __restrict__ er,
                                              const void* __restrict__ al2,
                                              const void* __restrict__ ar2,
                                              const int* __restrict__ flagp,
                                              int M, int N, int H) {
    __shared__ short Bs[64 * BSTRIDE];
    int isbf = flagp[0];
    stage_bt(Bs, W2, 64, 0, isbf, threadIdx.x);
    __syncthreads();
    gemm_core(Bs, A, C, el, er, al2, ar2, isbf, M, N, H, 1, blockIdx.x, 0);
}

// ---------------- layer-2 edges: wave per dst (H=1, D=64); ILP fast path ---------------
// Lean kernel (~35 VGPR, no LDS) -> (256,8) for 32 waves/CU on the latency-bound gather
// (r6's spill was the 4-accumulator edge1 at a 64-VGPR cap; this kernel fits easily).
__global__ __launch_bounds__(256, 8) void k_edge2(const int* __restrict__ cnt,
                        const int* __restrict__ bucket,
                        const float* __restrict__ el, const float* __restrict__ er,
                        const unsigned short* __restrict__ feat,
                        const void* __restrict__ b2,
                        void* __restrict__ out, const int* __restrict__ flagp) {
    int wave = threadIdx.x >> 6, lane = threadIdx.x & 63;
    int node = blockIdx.x * 4 + wave;
    if (node >= NN) return;
    int eg = lane >> 3, d8 = lane & 7;
    int isbf = flagp[0];
    int end = cnt[node]; if (end > BCAP) end = BCAP;
    const int* bkt = bucket + ((size_t)node << 7);
    float er_d = er[node];
    float lsum;
    float a[8] = {};

    if (end <= 64) {                              // fast path: one edge per lane
        int s = 0; float wgt = 0.f;
        if (lane < end) {
            s = bkt[lane];
            float x = el[s] + er_d;
            x = (x >= 0.f) ? x : 0.2f * x;
            wgt = __expf(x);
        }
        lsum = wgt;
        int niter = (end + 7) >> 3;
#pragma unroll 4
        for (int i = 0; i < niter; ++i) {
            int idx = 8 * i + eg;
            float we = __shfl(wgt, idx, 64);
            int   se = __shfl(s, idx, 64);
            u16x8 fv = *(const u16x8*)&feat[((size_t)se << 6) + (d8 << 3)];
#pragma unroll
            for (int j = 0; j < 8; ++j) a[j] += we * b2f(fv[j]);
        }
    } else {                                      // slow path: chunked (unused here)
        lsum = 0.f;
        for (int base = 0; base < end; base += 64) {
            int c = base + lane;
            float wgt = 0.f; int s = 0;
            if (c < end) {
                s = bkt[c];
                float x = el[s] + er_d;
                x = (x >= 0.f) ? x : 0.2f * x;
                wgt = __expf(x);
            }
            lsum += wgt;
            int cn = end - base; if (cn > 64) cn = 64;
            int niter = (cn + 7) >> 3;
#pragma unroll 2
            for (int i = 0; i < niter; ++i) {
                int idx = 8 * i + eg;
                float we = __shfl(wgt, idx, 64);
                int   se = __shfl(s, idx, 64);
                u16x8 fv = *(const u16x8*)&feat[((size_t)se << 6) + (d8 << 3)];
#pragma unroll
                for (int j = 0; j < 8; ++j) a[j] += we * b2f(fv[j]);
            }
        }
    }
#pragma unroll
    for (int o = 1; o < 64; o <<= 1) lsum += __shfl_xor(lsum, o, 64);
#pragma unroll
    for (int j = 0; j < 8; ++j) {
        a[j] += __shfl_xor(a[j], 8, 64);
        a[j] += __shfl_xor(a[j], 16, 64);
        a[j] += __shfl_xor(a[j], 32, 64);
    }
    if (eg == 0) {
        float inv = (lsum > 0.f) ? 1.f / lsum : 0.f;
        float o[8];
#pragma unroll
        for (int j = 0; j < 8; ++j) o[j] = a[j] * inv + ld_param(b2, d8 * 8 + j, isbf);
        size_t ob = ((size_t)node << 6) + d8 * 8;
        if (isbf) {
            u16x8 r;
#pragma unroll
            for (int j = 0; j < 8; ++j) r[j] = f2b(o[j]);
            *(u16x8*)&((unsigned short*)out)[ob] = r;
        } else {
            float4 r0, r1;
            r0.x = o[0]; r0.y = o[1]; r0.z = o[2]; r0.w = o[3];
            r1.x = o[4]; r1.y = o[5]; r1.z = o[6]; r1.w = o[7];
            *(float4*)&((float*)out)[ob] = r0;
            *(float4*)&((float*)out)[ob + 4] = r1;
        }
    }
}

extern "C" void kernel_launch(void* const* d_in, const int* in_sizes, int n_in,
                              void* d_out, int out_size, void* d_ws, size_t ws_size,
                              hipStream_t stream) {
    const void* h   = d_in[0];
    const int*  src = (const int*)d_in[1];
    const int*  dst = (const int*)d_in[2];
    const void* W1  = d_in[3];
    const void* al1 = d_in[4];
    const void* ar1 = d_in[5];
    const void* b1  = d_in[6];
    const void* W2  = d_in[7];
    const void* al2 = d_in[8];
    const void* ar2 = d_in[9];
    const void* b2  = d_in[10];

    char* w = (char*)d_ws;
    size_t off = 0;
    auto alloc = [&](size_t bytes) -> void* {
        void* p = w + off;
        off = (off + bytes + 255) & ~(size_t)255;
        return p;
    };
    int* flag               = (int*)alloc(8);
    int* cnt                = (int*)alloc(NN * 4);
    int* bucket             = (int*)alloc((size_t)NN * BCAP * 4);   // 5.12 MB
    unsigned short* feat1   = (unsigned short*)alloc((size_t)NN * 256 * 2);
    float* el1              = (float*)alloc(NN * NH * 4);
    float* er1              = (float*)alloc(NN * NH * 4);
    unsigned short* h1      = (unsigned short*)alloc((size_t)NN * 256 * 2);
    unsigned short* feat2   = (unsigned short*)alloc((size_t)NN * 64 * 2);
    float* el2              = (float*)alloc(NN * 4);
    float* er2              = (float*)alloc(NN * 4);
    (void)ws_size; (void)in_sizes; (void)n_in; (void)out_size;

    // 0: zero cnt (replaces prep's zeroing; graph-capturable memset node)
    hipMemsetAsync(cnt, 0, NN * sizeof(int), stream);
    // 1: layer-1 GEMM (self-contained: local isbf + inline W1 stage + inline al/ar)
    //    + bucket CSR build; block 0 publishes flag
    k_g1b<<<GEMM1_BLOCKS + BUILD_BLOCKS, 256, 0, stream>>>(h, W1, feat1, el1, er1,
                                                           al1, ar1, src, dst,
                                                           cnt, bucket, flag);
    // 2: layer-1 edge aggregate, head-sliced for L2 residency
    k_e1h<<<NN, 256, 0, stream>>>(cnt, bucket, el1, er1, feat1, b1, flag, h1);
    // 3: layer-2 GEMM (h1 bf16; W2 staged inline)
    k_gemm<<<dim3(GEMM1_MT, 1), 256, 0, stream>>>(h1, W2, feat2, el2, er2,
                                                  al2, ar2, flag, NN, 64, 1);
    // 4: layer-2 edge aggregate -> output
    k_edge2<<<(NN + 3) / 4, 256, 0, stream>>>(cnt, bucket, el2, er2, feat2, b2, d_out, flag);
}

// Round 10
// 148.586 us; speedup vs baseline: 1.0961x; 1.0961x over previous
//
#include <hip/hip_runtime.h>
#include <hip/hip_bf16.h>
#include <stdint.h>

#define NN 10000
#define NE 320000
#define NH 4
#define BCAP 128                     // per-node bucket capacity (max deg ~60 for this graph)

#define GEMM1_MT 157                 // ceil(10000/64) 64-row tiles per head
#define GEMM1_BLOCKS (GEMM1_MT * 4)
#define BUILD_BLOCKS 1250            // ceil(320000/256)

typedef __attribute__((ext_vector_type(8))) short s16x8;
typedef __attribute__((ext_vector_type(4))) float f32x4;
typedef __attribute__((ext_vector_type(8))) unsigned short u16x8;

static __device__ __forceinline__ float b2f(unsigned short u) {
    union { unsigned int i; float f; } x; x.i = ((unsigned int)u) << 16; return x.f;
}
static __device__ __forceinline__ unsigned short f2b(float f) {
    unsigned int u = __float_as_uint(f);
    unsigned int r = (u + 0x7fffu + ((u >> 16) & 1u)) >> 16;
    return (unsigned short)r;
}

// ---------------- fused prep: dtype flag + canon small tensors + W transposes + cnt zero ----
// (r9 lesson: this once-amortized transpose/detect must NOT be replicated per GEMM block —
// doing so cost +25us of per-block scalar staging. Keep the dedicated prep dispatch.)
__global__ __launch_bounds__(256) void k_prep(const unsigned short* __restrict__ hraw,
                        const void* __restrict__ W1, const void* __restrict__ W2,
                        const void* al1, const void* ar1, const void* b1,
                        const void* al2, const void* ar2, const void* b2,
                        unsigned short* __restrict__ W1T, unsigned short* __restrict__ W2T,
                        unsigned short* __restrict__ canon, int* __restrict__ cnt,
                        int* __restrict__ flag) {
    __shared__ int sb[256];
    int t = threadIdx.x;
    int c = 0;
    for (int i = t; i < 2048; i += 256) {       // 2048 samples: >20 sigma margin
        unsigned short u = hraw[i];
        int e = (u >> 7) & 0xFF;
        c += (e >= 97 && e <= 157) ? 1 : 0;     // |x| in [2^-30, 2^30]
    }
    sb[t] = c;
    __syncthreads();
    for (int o = 128; o > 0; o >>= 1) {
        if (t < o) sb[t] += sb[t + o];
        __syncthreads();
    }
    int isbf = (sb[0] >= 1741) ? 1 : 0;         // 85% of 2048

    int idx = blockIdx.x * 256 + t;
    if (idx < 65536) {                           // W1T[n*256+k] = W1[k*256+n]
        int n = idx >> 8, k = idx & 255;
        W1T[idx] = isbf ? ((const unsigned short*)W1)[k * 256 + n]
                        : f2b(((const float*)W1)[k * 256 + n]);
    } else if (idx < 81920) {                    // W2T[n*256+k] = W2[k*64+n]
        int j = idx - 65536;
        int n = j >> 8, k = j & 255;
        W2T[j] = isbf ? ((const unsigned short*)W2)[k * 64 + n]
                      : f2b(((const float*)W2)[k * 64 + n]);
    } else if (idx < 82880) {                    // small tensors -> canon
        int j = idx - 81920;
        const void* srcp; int q;
        if      (j < 256) { srcp = al1; q = j; }
        else if (j < 512) { srcp = ar1; q = j - 256; }
        else if (j < 768) { srcp = b1;  q = j - 512; }
        else if (j < 832) { srcp = al2; q = j - 768; }
        else if (j < 896) { srcp = ar2; q = j - 832; }
        else              { srcp = b2;  q = j - 896; }
        canon[j] = isbf ? ((const unsigned short*)srcp)[q] : f2b(((const float*)srcp)[q]);
    } else if (idx < 92880) {                    // zero cnt[10000]
        cnt[idx - 82880] = 0;
    } else if (idx == 92880) {
        flag[0] = isbf;
    }
}

// ---------------- GEMM body: 64 rows x one head's 64 cols, one-time LDS B-stage --------
#define BSTRIDE 264   // shorts; 528B row: 16B-aligned, bank rotation 4r mod 32
static __device__ __forceinline__ void gemm_body(short* Bs,
                        const void* __restrict__ A, const unsigned short* __restrict__ BT,
                        unsigned short* __restrict__ C,
                        float* __restrict__ el, float* __restrict__ er,
                        const unsigned short* __restrict__ al,
                        const unsigned short* __restrict__ ar,
                        int M, int N, int H, int a_isbf, int mtile, int head) {
    int t = threadIdx.x;
    int wave = t >> 6, lane = t & 63;
    int m0 = mtile * 64;
    const unsigned short* Bh = BT + (size_t)head * 64 * 256;

    // stage B: 64 rows x 256 shorts = 2048 x 16B chunks; 8 chunks/thread
#pragma unroll
    for (int i = 0; i < 8; ++i) {
        int idx = t + i * 256;
        int row = idx >> 5, chunk = idx & 31;
        *(s16x8*)&Bs[row * BSTRIDE + chunk * 8] =
            *(const s16x8*)&Bh[(size_t)row * 256 + chunk * 8];
    }
    __syncthreads();

    int kq = (lane >> 4) * 8;
    const unsigned short* Ab = (const unsigned short*)A;
    const float*          Af = (const float*)A;
    int aRow = m0 + wave * 16 + (lane & 15);
    int aR = (aRow < M) ? aRow : M - 1;          // clamp loads; stores guarded
    f32x4 acc[4] = {};

#pragma unroll
    for (int k0 = 0; k0 < 256; k0 += 32) {
        s16x8 afr;
        if (a_isbf) {
            afr = *(const s16x8*)&Ab[(size_t)aR * 256 + k0 + kq];
        } else {
            const float* pf = &Af[(size_t)aR * 256 + k0 + kq];
            float4 x0 = *(const float4*)pf;
            float4 x1 = *(const float4*)(pf + 4);
            afr[0] = (short)f2b(x0.x); afr[1] = (short)f2b(x0.y);
            afr[2] = (short)f2b(x0.z); afr[3] = (short)f2b(x0.w);
            afr[4] = (short)f2b(x1.x); afr[5] = (short)f2b(x1.y);
            afr[6] = (short)f2b(x1.z); afr[7] = (short)f2b(x1.w);
        }
#pragma unroll
        for (int nt = 0; nt < 4; ++nt) {
            s16x8 bfr = *(const s16x8*)&Bs[(nt * 16 + (lane & 15)) * BSTRIDE + k0 + kq];
            acc[nt] = __builtin_amdgcn_mfma_f32_16x16x32_bf16(afr, bfr, acc[nt], 0, 0, 0);
        }
    }

    float alv[4], arv[4];
#pragma unroll
    for (int nt = 0; nt < 4; ++nt) {
        int c = (lane & 15) + nt * 16;
        alv[nt] = b2f(al[head * 64 + c]);
        arv[nt] = b2f(ar[head * 64 + c]);
    }
    int col0 = head * 64 + (lane & 15);
    int r0 = m0 + wave * 16 + (lane >> 4) * 4;
    float cr[4][4];
#pragma unroll
    for (int nt = 0; nt < 4; ++nt) {
        int col = col0 + nt * 16;
#pragma unroll
        for (int i = 0; i < 4; ++i) {
            unsigned short cb = f2b(acc[nt][i]);
            cr[nt][i] = b2f(cb);
            int r = r0 + i;
            if (r < M) C[(size_t)r * N + col] = cb;
        }
    }
#pragma unroll
    for (int i = 0; i < 4; ++i) {
        float pl = 0.f, pr = 0.f;
#pragma unroll
        for (int nt = 0; nt < 4; ++nt) {
            pl += cr[nt][i] * alv[nt];
            pr += cr[nt][i] * arv[nt];
        }
#pragma unroll
        for (int o = 1; o < 16; o <<= 1) {
            pl += __shfl_xor(pl, o, 64);
            pr += __shfl_xor(pr, o, 64);
        }
        int r = r0 + i;
        if ((lane & 15) == 0 && r < M) {
            el[(size_t)r * H + head] = pl;
            er[(size_t)r * H + head] = pr;
        }
    }
}

// ---------------- fused: layer-1 GEMM (blocks 0..627) + bucket CSR build (628..1877) ----
__global__ __launch_bounds__(256) void k_g1b(const void* __restrict__ A,
                        const unsigned short* __restrict__ W1T,
                        unsigned short* __restrict__ feat1,
                        float* __restrict__ el, float* __restrict__ er,
                        const unsigned short* __restrict__ al,
                        const unsigned short* __restrict__ ar,
                        const int* __restrict__ flagp,
                        const int* __restrict__ src, const int* __restrict__ dst,
                        int* __restrict__ cnt, int* __restrict__ bucket) {
    __shared__ short Bs[64 * BSTRIDE];
    int bid = blockIdx.x;
    if (bid < GEMM1_BLOCKS) {
        int head = bid / GEMM1_MT;
        int mtile = bid - head * GEMM1_MT;
        gemm_body(Bs, A, W1T, feat1, el, er, al, ar, NN, 256, NH, flagp[0], mtile, head);
    } else {
        int i = (bid - GEMM1_BLOCKS) * 256 + threadIdx.x;
        if (i < NE) {
            int d = dst[i];
            int pos = atomicAdd(&cnt[d], 1);
            if (pos < BCAP) bucket[(d << 7) + pos] = src[i];   // cap unreachable: max deg ~60
        }
    }
}

// ---------------- layer-1 edges: HEAD-SLICED wave per (node, head) ---------------------
// Head-major grid (blocks 0..2499 -> head 0, etc): all ~1500 concurrently-resident blocks
// gather from the SAME head's feat1 slab = 10000 x 128B lines = 1.28MB -> L2-RESIDENT on
// every XCD (r8: -4.2us vs interleaved heads). Per-(head,j) accumulation order ascending
// edge index with the same shfl reductions -> bit-identical h1. No LDS; (256,8).
__global__ __launch_bounds__(256, 8) void k_e1h(const int* __restrict__ cnt,
                        const int* __restrict__ bucket,
                        const float* __restrict__ el, const float* __restrict__ er,
                        const unsigned short* __restrict__ feat,
                        const unsigned short* __restrict__ b1,
                        unsigned short* __restrict__ h1) {
    int wave = threadIdx.x >> 6, lane = threadIdx.x & 63;
    int bid = blockIdx.x;
    int head = bid / 2500;                        // head-major: locality window = 1 slab
    int node = (bid - head * 2500) * 4 + wave;    // 2500*4 == 10000 exactly
    int eg = lane >> 3, d8 = lane & 7;
    int end = cnt[node]; if (end > BCAP) end = BCAP;
    const int* bkt = bucket + ((size_t)node << 7);
    float er_d = er[(size_t)node * 4 + head];

    if (end <= 64) {                              // fast path: one edge per lane
        int s = 0; float w = 0.f;
        if (lane < end) {
            s = bkt[lane];
            float x = el[(size_t)s * 4 + head] + er_d;
            x = (x >= 0.f) ? x : 0.2f * x;
            w = __expf(x);                        // |x| ~ O(1): shift-free softmax
        }
        float ls = w;
#pragma unroll
        for (int o = 1; o < 64; o <<= 1) ls += __shfl_xor(ls, o, 64);
        float a[8] = {};
        int niter = (end + 7) >> 3;
#pragma unroll 4
        for (int i = 0; i < niter; ++i) {
            int idx = 8 * i + eg;
            int   se = __shfl(s, idx, 64);
            float we = __shfl(w, idx, 64);
            u16x8 fv = *(const u16x8*)&feat[(((size_t)se * NH + head) << 6) + (d8 << 3)];
#pragma unroll
            for (int j = 0; j < 8; ++j) a[j] += we * b2f(fv[j]);
        }
#pragma unroll
        for (int j = 0; j < 8; ++j) {
            a[j] += __shfl_xor(a[j], 8, 64);
            a[j] += __shfl_xor(a[j], 16, 64);
            a[j] += __shfl_xor(a[j], 32, 64);
        }
        if (eg == 0) {
            float inv = (ls > 0.f) ? 1.f / ls : 0.f;
            u16x8 r;
#pragma unroll
            for (int j = 0; j < 8; ++j) {
                float o = a[j] * inv + b2f(b1[head * 64 + d8 * 8 + j]);
                o = (o > 0.f) ? o : (__expf(o) - 1.f);   // ELU
                r[j] = f2b(o);
            }
            *(u16x8*)&h1[(((size_t)node * NH + head) << 6) + d8 * 8] = r;
        }
    } else {                                      // slow path: chunked (deg > 64; unused here)
        float a[8] = {};
        float ls = 0.f;
        for (int base = 0; base < end; base += 64) {
            int c = base + lane;
            int s = 0; float w = 0.f;
            if (c < end) {
                s = bkt[c];
                float x = el[(size_t)s * 4 + head] + er_d;
                x = (x >= 0.f) ? x : 0.2f * x;
                w = __expf(x);
            }
            ls += w;
            int cn = end - base; if (cn > 64) cn = 64;
            int niter = (cn + 7) >> 3;
#pragma unroll 2
            for (int i = 0; i < niter; ++i) {
                int idx = 8 * i + eg;
                int   se = __shfl(s, idx, 64);
                float we = __shfl(w, idx, 64);
                u16x8 fv = *(const u16x8*)&feat[(((size_t)se * NH + head) << 6) + (d8 << 3)];
#pragma unroll
                for (int j = 0; j < 8; ++j) a[j] += we * b2f(fv[j]);
            }
        }
#pragma unroll
        for (int o = 1; o < 64; o <<= 1) ls += __shfl_xor(ls, o, 64);
#pragma unroll
        for (int j = 0; j < 8; ++j) {
            a[j] += __shfl_xor(a[j], 8, 64);
            a[j] += __shfl_xor(a[j], 16, 64);
            a[j] += __shfl_xor(a[j], 32, 64);
        }
        if (eg == 0) {
            float inv = (ls > 0.f) ? 1.f / ls : 0.f;
            u16x8 r;
#pragma unroll
            for (int j = 0; j < 8; ++j) {
                float o = a[j] * inv + b2f(b1[head * 64 + d8 * 8 + j]);
                o = (o > 0.f) ? o : (__expf(o) - 1.f);
                r[j] = f2b(o);
            }
            *(u16x8*)&h1[(((size_t)node * NH + head) << 6) + d8 * 8] = r;
        }
    }
}

// ---------------- standalone GEMM for layer 2 (A=h1, known bf16, H=1) ----------------
__global__ __launch_bounds__(256) void k_gemm(const void* __restrict__ A,
                                              const unsigned short* __restrict__ BT,
                                              unsigned short* __restrict__ C,
                                              float* __restrict__ el, float* __restrict__ er,
                                              const unsigned short* __restrict__ al,
                                              const unsigned short* __restrict__ ar,
                                              int M, int N, int H) {
    __shared__ short Bs[64 * BSTRIDE];
    gemm_body(Bs, A, BT, C, el, er, al, ar, M, N, H, 1, blockIdx.x, blockIdx.y);
}

// ---------------- layer-2 edges: wave per dst (H=1, D=64); ILP fast path ---------------
// ONLY change vs r8: (256,4) -> (256,8). Lean kernel (~35-45 VGPR: 8 accumulators + one
// 8-wide gather temp; r6's spill was edge1's 4x that) -> 32 waves/CU doubles outstanding
// misses on the latency-bound feat2 gather (1.28MB, L2-resident).
__global__ __launch_bounds__(256, 8) void k_edge2(const int* __restrict__ cnt,
                        const int* __restrict__ bucket,
                        const float* __restrict__ el, const float* __restrict__ er,
                        const unsigned short* __restrict__ feat,
                        const unsigned short* __restrict__ b2,
                        void* __restrict__ out, const int* __restrict__ flagp) {
    int wave = threadIdx.x >> 6, lane = threadIdx.x & 63;
    int node = blockIdx.x * 4 + wave;
    if (node >= NN) return;
    int eg = lane >> 3, d8 = lane & 7;
    int isbf = flagp[0];
    int end = cnt[node]; if (end > BCAP) end = BCAP;
    const int* bkt = bucket + ((size_t)node << 7);
    float er_d = er[node];
    float lsum;
    float a[8] = {};

    if (end <= 64) {                              // fast path: one edge per lane
        int s = 0; float wgt = 0.f;
        if (lane < end) {
            s = bkt[lane];
            float x = el[s] + er_d;
            x = (x >= 0.f) ? x : 0.2f * x;
            wgt = __expf(x);
        }
        lsum = wgt;
        int niter = (end + 7) >> 3;
#pragma unroll 4
        for (int i = 0; i < niter; ++i) {
            int idx = 8 * i + eg;
            float we = __shfl(wgt, idx, 64);
            int   se = __shfl(s, idx, 64);
            u16x8 fv = *(const u16x8*)&feat[((size_t)se << 6) + (d8 << 3)];
#pragma unroll
            for (int j = 0; j < 8; ++j) a[j] += we * b2f(fv[j]);
        }
    } else {                                      // slow path: chunked (unused here)
        lsum = 0.f;
        for (int base = 0; base < end; base += 64) {
            int c = base + lane;
            float wgt = 0.f; int s = 0;
            if (c < end) {
                s = bkt[c];
                float x = el[s] + er_d;
                x = (x >= 0.f) ? x : 0.2f * x;
                wgt = __expf(x);
            }
            lsum += wgt;
            int cn = end - base; if (cn > 64) cn = 64;
            int niter = (cn + 7) >> 3;
#pragma unroll 2
            for (int i = 0; i < niter; ++i) {
                int idx = 8 * i + eg;
                float we = __shfl(wgt, idx, 64);
                int   se = __shfl(s, idx, 64);
                u16x8 fv = *(const u16x8*)&feat[((size_t)se << 6) + (d8 << 3)];
#pragma unroll
                for (int j = 0; j < 8; ++j) a[j] += we * b2f(fv[j]);
            }
        }
    }
#pragma unroll
    for (int o = 1; o < 64; o <<= 1) lsum += __shfl_xor(lsum, o, 64);
#pragma unroll
    for (int j = 0; j < 8; ++j) {
        a[j] += __shfl_xor(a[j], 8, 64);
        a[j] += __shfl_xor(a[j], 16, 64);
        a[j] += __shfl_xor(a[j], 32, 64);
    }
    if (eg == 0) {
        float inv = (lsum > 0.f) ? 1.f / lsum : 0.f;
        float o[8];
#pragma unroll
        for (int j = 0; j < 8; ++j) o[j] = a[j] * inv + b2f(b2[d8 * 8 + j]);
        size_t ob = ((size_t)node << 6) + d8 * 8;
        if (isbf) {
            u16x8 r;
#pragma unroll
            for (int j = 0; j < 8; ++j) r[j] = f2b(o[j]);
            *(u16x8*)&((unsigned short*)out)[ob] = r;
        } else {
            float4 r0, r1;
            r0.x = o[0]; r0.y = o[1]; r0.z = o[2]; r0.w = o[3];
            r1.x = o[4]; r1.y = o[5]; r1.z = o[6]; r1.w = o[7];
            *(float4*)&((float*)out)[ob] = r0;
            *(float4*)&((float*)out)[ob + 4] = r1;
        }
    }
}

extern "C" void kernel_launch(void* const* d_in, const int* in_sizes, int n_in,
                              void* d_out, int out_size, void* d_ws, size_t ws_size,
                              hipStream_t stream) {
    const void* h   = d_in[0];
    const int*  src = (const int*)d_in[1];
    const int*  dst = (const int*)d_in[2];
    const void* W1  = d_in[3];
    const void* al1 = d_in[4];
    const void* ar1 = d_in[5];
    const void* b1  = d_in[6];
    const void* W2  = d_in[7];
    const void* al2 = d_in[8];
    const void* ar2 = d_in[9];
    const void* b2  = d_in[10];

    char* w = (char*)d_ws;
    size_t off = 0;
    auto alloc = [&](size_t bytes) -> void* {
        void* p = w + off;
        off = (off + bytes + 255) & ~(size_t)255;
        return p;
    };
    int* flag               = (int*)alloc(8);
    int* cnt                = (int*)alloc(NN * 4);
    int* bucket             = (int*)alloc((size_t)NN * BCAP * 4);   // 5.12 MB
    unsigned short* canon   = (unsigned short*)alloc(960 * 2);
    unsigned short* W1T     = (unsigned short*)alloc(256 * 256 * 2);
    unsigned short* W2T     = (unsigned short*)alloc(64 * 256 * 2);
    unsigned short* feat1   = (unsigned short*)alloc((size_t)NN * 256 * 2);
    float* el1              = (float*)alloc(NN * NH * 4);
    float* er1              = (float*)alloc(NN * NH * 4);
    unsigned short* h1      = (unsigned short*)alloc((size_t)NN * 256 * 2);
    unsigned short* feat2   = (unsigned short*)alloc((size_t)NN * 64 * 2);
    float* el2              = (float*)alloc(NN * 4);
    float* er2              = (float*)alloc(NN * 4);
    (void)ws_size; (void)in_sizes; (void)n_in; (void)out_size;

    unsigned short* cal1 = canon + 0;
    unsigned short* car1 = canon + 256;
    unsigned short* cb1  = canon + 512;
    unsigned short* cal2 = canon + 768;
    unsigned short* car2 = canon + 832;
    unsigned short* cb2  = canon + 896;

    // 1: prep (flag + canon + transposes + cnt zero)
    k_prep<<<363, 256, 0, stream>>>((const unsigned short*)h, W1, W2,
                                    al1, ar1, b1, al2, ar2, b2,
                                    W1T, W2T, canon, cnt, flag);
    // 2: layer-1 GEMM (64-row tiles, 628 blocks) + bucket CSR build (one dispatch)
    k_g1b<<<GEMM1_BLOCKS + BUILD_BLOCKS, 256, 0, stream>>>(h, W1T, feat1, el1, er1,
                                                           cal1, car1, flag,
                                                           src, dst, cnt, bucket);
    // 3: layer-1 edge aggregate, head-sliced for L2 residency (head-major grid)
    k_e1h<<<NN, 256, 0, stream>>>(cnt, bucket, el1, er1, feat1, cb1, h1);
    // 4: layer-2 GEMM (h1 known bf16)
    k_gemm<<<dim3(GEMM1_MT, 1), 256, 0, stream>>>(h1, W2T, feat2, el2, er2,
                                                  cal2, car2, NN, 64, 1);
    // 5: layer-2 edge aggregate -> output
    k_edge2<<<(NN + 3) / 4, 256, 0, stream>>>(cnt, bucket, el2, er2, feat2, cb2, d_out, flag);
}

// Round 11
// 146.620 us; speedup vs baseline: 1.1108x; 1.0134x over previous
//
#include <hip/hip_runtime.h>
#include <hip/hip_bf16.h>
#include <stdint.h>

#define NN 10000
#define NE 320000
#define NH 4
#define BCAP 128                     // per-node bucket capacity (max deg ~60 for this graph)
#define ELP 10240                    // el1t pitch (floats): head-major el slab, 40KB/head

#define GEMM1_MT 157                 // ceil(10000/64) 64-row tiles per head
#define GEMM1_BLOCKS (GEMM1_MT * 4)
#define BUILD_BLOCKS 1250            // ceil(320000/256)

typedef __attribute__((ext_vector_type(8))) short s16x8;
typedef __attribute__((ext_vector_type(4))) float f32x4;
typedef __attribute__((ext_vector_type(8))) unsigned short u16x8;

static __device__ __forceinline__ float b2f(unsigned short u) {
    union { unsigned int i; float f; } x; x.i = ((unsigned int)u) << 16; return x.f;
}
static __device__ __forceinline__ unsigned short f2b(float f) {
    unsigned int u = __float_as_uint(f);
    unsigned int r = (u + 0x7fffu + ((u >> 16) & 1u)) >> 16;
    return (unsigned short)r;
}

// ---------------- fused prep: dtype flag + canon small tensors + W transposes + cnt zero ----
// (r9 lesson: once-amortized transpose/detect must NOT be replicated per GEMM block.)
__global__ __launch_bounds__(256) void k_prep(const unsigned short* __restrict__ hraw,
                        const void* __restrict__ W1, const void* __restrict__ W2,
                        const void* al1, const void* ar1, const void* b1,
                        const void* al2, const void* ar2, const void* b2,
                        unsigned short* __restrict__ W1T, unsigned short* __restrict__ W2T,
                        unsigned short* __restrict__ canon, int* __restrict__ cnt,
                        int* __restrict__ flag) {
    __shared__ int sb[256];
    int t = threadIdx.x;
    int c = 0;
    for (int i = t; i < 2048; i += 256) {       // 2048 samples: >20 sigma margin
        unsigned short u = hraw[i];
        int e = (u >> 7) & 0xFF;
        c += (e >= 97 && e <= 157) ? 1 : 0;     // |x| in [2^-30, 2^30]
    }
    sb[t] = c;
    __syncthreads();
    for (int o = 128; o > 0; o >>= 1) {
        if (t < o) sb[t] += sb[t + o];
        __syncthreads();
    }
    int isbf = (sb[0] >= 1741) ? 1 : 0;         // 85% of 2048

    int idx = blockIdx.x * 256 + t;
    if (idx < 65536) {                           // W1T[n*256+k] = W1[k*256+n]
        int n = idx >> 8, k = idx & 255;
        W1T[idx] = isbf ? ((const unsigned short*)W1)[k * 256 + n]
                        : f2b(((const float*)W1)[k * 256 + n]);
    } else if (idx < 81920) {                    // W2T[n*256+k] = W2[k*64+n]
        int j = idx - 65536;
        int n = j >> 8, k = j & 255;
        W2T[j] = isbf ? ((const unsigned short*)W2)[k * 64 + n]
                      : f2b(((const float*)W2)[k * 64 + n]);
    } else if (idx < 82880) {                    // small tensors -> canon
        int j = idx - 81920;
        const void* srcp; int q;
        if      (j < 256) { srcp = al1; q = j; }
        else if (j < 512) { srcp = ar1; q = j - 256; }
        else if (j < 768) { srcp = b1;  q = j - 512; }
        else if (j < 832) { srcp = al2; q = j - 768; }
        else if (j < 896) { srcp = ar2; q = j - 832; }
        else              { srcp = b2;  q = j - 896; }
        canon[j] = isbf ? ((const unsigned short*)srcp)[q] : f2b(((const float*)srcp)[q]);
    } else if (idx < 92880) {                    // zero cnt[10000]
        cnt[idx - 82880] = 0;
    } else if (idx == 92880) {
        flag[0] = isbf;
    }
}

// ---------------- GEMM body: 64 rows x one head's 64 cols, one-time LDS B-stage --------
// el is written HEAD-MAJOR: el[head*elpitch + r] (elpitch=ELP for layer 1 -> 40KB/head
// slab so e1h's random el-gathers become ~L1 hits; elpitch irrelevant for H=1/head=0).
#define BSTRIDE 264   // shorts; 528B row: 16B-aligned, bank rotation 4r mod 32
static __device__ __forceinline__ void gemm_body(short* Bs,
                        const void* __restrict__ A, const unsigned short* __restrict__ BT,
                        unsigned short* __restrict__ C,
                        float* __restrict__ el, float* __restrict__ er,
                        const unsigned short* __restrict__ al,
                        const unsigned short* __restrict__ ar,
                        int M, int N, int H, int a_isbf, int mtile, int head, int elpitch) {
    int t = threadIdx.x;
    int wave = t >> 6, lane = t & 63;
    int m0 = mtile * 64;
    const unsigned short* Bh = BT + (size_t)head * 64 * 256;

    // stage B: 64 rows x 256 shorts = 2048 x 16B chunks; 8 chunks/thread
#pragma unroll
    for (int i = 0; i < 8; ++i) {
        int idx = t + i * 256;
        int row = idx >> 5, chunk = idx & 31;
        *(s16x8*)&Bs[row * BSTRIDE + chunk * 8] =
            *(const s16x8*)&Bh[(size_t)row * 256 + chunk * 8];
    }
    __syncthreads();

    int kq = (lane >> 4) * 8;
    const unsigned short* Ab = (const unsigned short*)A;
    const float*          Af = (const float*)A;
    int aRow = m0 + wave * 16 + (lane & 15);
    int aR = (aRow < M) ? aRow : M - 1;          // clamp loads; stores guarded
    f32x4 acc[4] = {};

#pragma unroll
    for (int k0 = 0; k0 < 256; k0 += 32) {
        s16x8 afr;
        if (a_isbf) {
            afr = *(const s16x8*)&Ab[(size_t)aR * 256 + k0 + kq];
        } else {
            const float* pf = &Af[(size_t)aR * 256 + k0 + kq];
            float4 x0 = *(const float4*)pf;
            float4 x1 = *(const float4*)(pf + 4);
            afr[0] = (short)f2b(x0.x); afr[1] = (short)f2b(x0.y);
            afr[2] = (short)f2b(x0.z); afr[3] = (short)f2b(x0.w);
            afr[4] = (short)f2b(x1.x); afr[5] = (short)f2b(x1.y);
            afr[6] = (short)f2b(x1.z); afr[7] = (short)f2b(x1.w);
        }
#pragma unroll
        for (int nt = 0; nt < 4; ++nt) {
            s16x8 bfr = *(const s16x8*)&Bs[(nt * 16 + (lane & 15)) * BSTRIDE + k0 + kq];
            acc[nt] = __builtin_amdgcn_mfma_f32_16x16x32_bf16(afr, bfr, acc[nt], 0, 0, 0);
        }
    }

    float alv[4], arv[4];
#pragma unroll
    for (int nt = 0; nt < 4; ++nt) {
        int c = (lane & 15) + nt * 16;
        alv[nt] = b2f(al[head * 64 + c]);
        arv[nt] = b2f(ar[head * 64 + c]);
    }
    int col0 = head * 64 + (lane & 15);
    int r0 = m0 + wave * 16 + (lane >> 4) * 4;
    float cr[4][4];
#pragma unroll
    for (int nt = 0; nt < 4; ++nt) {
        int col = col0 + nt * 16;
#pragma unroll
        for (int i = 0; i < 4; ++i) {
            unsigned short cb = f2b(acc[nt][i]);
            cr[nt][i] = b2f(cb);
            int r = r0 + i;
            if (r < M) C[(size_t)r * N + col] = cb;
        }
    }
#pragma unroll
    for (int i = 0; i < 4; ++i) {
        float pl = 0.f, pr = 0.f;
#pragma unroll
        for (int nt = 0; nt < 4; ++nt) {
            pl += cr[nt][i] * alv[nt];
            pr += cr[nt][i] * arv[nt];
        }
#pragma unroll
        for (int o = 1; o < 16; o <<= 1) {
            pl += __shfl_xor(pl, o, 64);
            pr += __shfl_xor(pr, o, 64);
        }
        int r = r0 + i;
        if ((lane & 15) == 0 && r < M) {
            el[(size_t)head * elpitch + r] = pl;   // head-major el
            er[(size_t)r * H + head] = pr;         // er stays per-dst [node][head]
        }
    }
}

// ---------------- fused: layer-1 GEMM (blocks 0..627) + bucket CSR build (628..1877) ----
__global__ __launch_bounds__(256) void k_g1b(const void* __restrict__ A,
                        const unsigned short* __restrict__ W1T,
                        unsigned short* __restrict__ feat1,
                        float* __restrict__ el, float* __restrict__ er,
                        const unsigned short* __restrict__ al,
                        const unsigned short* __restrict__ ar,
                        const int* __restrict__ flagp,
                        const int* __restrict__ src, const int* __restrict__ dst,
                        int* __restrict__ cnt, int* __restrict__ bucket) {
    __shared__ short Bs[64 * BSTRIDE];
    int bid = blockIdx.x;
    if (bid < GEMM1_BLOCKS) {
        int head = bid / GEMM1_MT;
        int mtile = bid - head * GEMM1_MT;
        gemm_body(Bs, A, W1T, feat1, el, er, al, ar, NN, 256, NH, flagp[0], mtile, head, ELP);
    } else {
        int i = (bid - GEMM1_BLOCKS) * 256 + threadIdx.x;
        if (i < NE) {
            int d = dst[i];
            int pos = atomicAdd(&cnt[d], 1);
            if (pos < BCAP) bucket[(d << 7) + pos] = src[i];   // cap unreachable: max deg ~60
        }
    }
}

// ---------------- layer-1 edges: HEAD-SLICED wave per (node, head) ---------------------
// Head-major grid: resident blocks gather from ONE head's 1.28MB feat1 slab (L2-resident,
// r8) AND one head's 40KB el1t slab (~L1-resident after this round's transpose — the old
// [node][head] layout dragged a 64B line from a 640KB footprint per edge: ~82MB of L2
// traffic across heads, now ~4MB). Same values, same order -> bit-identical h1.
__global__ __launch_bounds__(256, 8) void k_e1h(const int* __restrict__ cnt,
                        const int* __restrict__ bucket,
                        const float* __restrict__ elt, const float* __restrict__ er,
                        const unsigned short* __restrict__ feat,
                        const unsigned short* __restrict__ b1,
                        unsigned short* __restrict__ h1) {
    int wave = threadIdx.x >> 6, lane = threadIdx.x & 63;
    int bid = blockIdx.x;
    int head = bid / 2500;                        // head-major: locality window = 1 slab
    int node = (bid - head * 2500) * 4 + wave;    // 2500*4 == 10000 exactly
    int eg = lane >> 3, d8 = lane & 7;
    int end = cnt[node]; if (end > BCAP) end = BCAP;
    const int* bkt = bucket + ((size_t)node << 7);
    const float* elh = elt + (size_t)head * ELP;  // this head's 40KB el slab
    float er_d = er[(size_t)node * 4 + head];

    if (end <= 64) {                              // fast path: one edge per lane
        int s = 0; float w = 0.f;
        if (lane < end) {
            s = bkt[lane];
            float x = elh[s] + er_d;
            x = (x >= 0.f) ? x : 0.2f * x;
            w = __expf(x);                        // |x| ~ O(1): shift-free softmax
        }
        float ls = w;
#pragma unroll
        for (int o = 1; o < 64; o <<= 1) ls += __shfl_xor(ls, o, 64);
        float a[8] = {};
        int niter = (end + 7) >> 3;
#pragma unroll 4
        for (int i = 0; i < niter; ++i) {
            int idx = 8 * i + eg;
            int   se = __shfl(s, idx, 64);
            float we = __shfl(w, idx, 64);
            u16x8 fv = *(const u16x8*)&feat[(((size_t)se * NH + head) << 6) + (d8 << 3)];
#pragma unroll
            for (int j = 0; j < 8; ++j) a[j] += we * b2f(fv[j]);
        }
#pragma unroll
        for (int j = 0; j < 8; ++j) {
            a[j] += __shfl_xor(a[j], 8, 64);
            a[j] += __shfl_xor(a[j], 16, 64);
            a[j] += __shfl_xor(a[j], 32, 64);
        }
        if (eg == 0) {
            float inv = (ls > 0.f) ? 1.f / ls : 0.f;
            u16x8 r;
#pragma unroll
            for (int j = 0; j < 8; ++j) {
                float o = a[j] * inv + b2f(b1[head * 64 + d8 * 8 + j]);
                o = (o > 0.f) ? o : (__expf(o) - 1.f);   // ELU
                r[j] = f2b(o);
            }
            *(u16x8*)&h1[(((size_t)node * NH + head) << 6) + d8 * 8] = r;
        }
    } else {                                      // slow path: chunked (deg > 64; unused here)
        float a[8] = {};
        float ls = 0.f;
        for (int base = 0; base < end; base += 64) {
            int c = base + lane;
            int s = 0; float w = 0.f;
            if (c < end) {
                s = bkt[c];
                float x = elh[s] + er_d;
                x = (x >= 0.f) ? x : 0.2f * x;
                w = __expf(x);
            }
            ls += w;
            int cn = end - base; if (cn > 64) cn = 64;
            int niter = (cn + 7) >> 3;
#pragma unroll 2
            for (int i = 0; i < niter; ++i) {
                int idx = 8 * i + eg;
                int   se = __shfl(s, idx, 64);
                float we = __shfl(w, idx, 64);
                u16x8 fv = *(const u16x8*)&feat[(((size_t)se * NH + head) << 6) + (d8 << 3)];
#pragma unroll
                for (int j = 0; j < 8; ++j) a[j] += we * b2f(fv[j]);
            }
        }
#pragma unroll
        for (int o = 1; o < 64; o <<= 1) ls += __shfl_xor(ls, o, 64);
#pragma unroll
        for (int j = 0; j < 8; ++j) {
            a[j] += __shfl_xor(a[j], 8, 64);
            a[j] += __shfl_xor(a[j], 16, 64);
            a[j] += __shfl_xor(a[j], 32, 64);
        }
        if (eg == 0) {
            float inv = (ls > 0.f) ? 1.f / ls : 0.f;
            u16x8 r;
#pragma unroll
            for (int j = 0; j < 8; ++j) {
                float o = a[j] * inv + b2f(b1[head * 64 + d8 * 8 + j]);
                o = (o > 0.f) ? o : (__expf(o) - 1.f);
                r[j] = f2b(o);
            }
            *(u16x8*)&h1[(((size_t)node * NH + head) << 6) + d8 * 8] = r;
        }
    }
}

// ---------------- standalone GEMM for layer 2 (A=h1, known bf16, H=1) ----------------
// head=0 -> el[0*pitch + r] == el2[r]: unchanged layout for layer 2.
__global__ __launch_bounds__(256) void k_gemm(const void* __restrict__ A,
                                              const unsigned short* __restrict__ BT,
                                              unsigned short* __restrict__ C,
                                              float* __restrict__ el, float* __restrict__ er,
                                              const unsigned short* __restrict__ al,
                                              const unsigned short* __restrict__ ar,
                                              int M, int N, int H) {
    __shared__ short Bs[64 * BSTRIDE];
    gemm_body(Bs, A, BT, C, el, er, al, ar, M, N, H, 1, blockIdx.x, 0, 0);
}

// ---------------- layer-2 edges: wave per dst (H=1, D=64); ILP fast path ---------------
// el2 is already a compact 40KB [NN] slab (L1-friendly); feat2 slab 1.28MB L2-resident.
__global__ __launch_bounds__(256, 8) void k_edge2(const int* __restrict__ cnt,
                        const int* __restrict__ bucket,
                        const float* __restrict__ el, const float* __restrict__ er,
                        const unsigned short* __restrict__ feat,
                        const unsigned short* __restrict__ b2,
                        void* __restrict__ out, const int* __restrict__ flagp) {
    int wave = threadIdx.x >> 6, lane = threadIdx.x & 63;
    int node = blockIdx.x * 4 + wave;
    if (node >= NN) return;
    int eg = lane >> 3, d8 = lane & 7;
    int isbf = flagp[0];
    int end = cnt[node]; if (end > BCAP) end = BCAP;
    const int* bkt = bucket + ((size_t)node << 7);
    float er_d = er[node];
    float lsum;
    float a[8] = {};

    if (end <= 64) {                              // fast path: one edge per lane
        int s = 0; float wgt = 0.f;
        if (lane < end) {
            s = bkt[lane];
            float x = el[s] + er_d;
            x = (x >= 0.f) ? x : 0.2f * x;
            wgt = __expf(x);
        }
        lsum = wgt;
        int niter = (end + 7) >> 3;
#pragma unroll 4
        for (int i = 0; i < niter; ++i) {
            int idx = 8 * i + eg;
            float we = __shfl(wgt, idx, 64);
            int   se = __shfl(s, idx, 64);
            u16x8 fv = *(const u16x8*)&feat[((size_t)se << 6) + (d8 << 3)];
#pragma unroll
            for (int j = 0; j < 8; ++j) a[j] += we * b2f(fv[j]);
        }
    } else {                                      // slow path: chunked (unused here)
        lsum = 0.f;
        for (int base = 0; base < end; base += 64) {
            int c = base + lane;
            float wgt = 0.f; int s = 0;
            if (c < end) {
                s = bkt[c];
                float x = el[s] + er_d;
                x = (x >= 0.f) ? x : 0.2f * x;
                wgt = __expf(x);
            }
            lsum += wgt;
            int cn = end - base; if (cn > 64) cn = 64;
            int niter = (cn + 7) >> 3;
#pragma unroll 2
            for (int i = 0; i < niter; ++i) {
                int idx = 8 * i + eg;
                float we = __shfl(wgt, idx, 64);
                int   se = __shfl(s, idx, 64);
                u16x8 fv = *(const u16x8*)&feat[((size_t)se << 6) + (d8 << 3)];
#pragma unroll
                for (int j = 0; j < 8; ++j) a[j] += we * b2f(fv[j]);
            }
        }
    }
#pragma unroll
    for (int o = 1; o < 64; o <<= 1) lsum += __shfl_xor(lsum, o, 64);
#pragma unroll
    for (int j = 0; j < 8; ++j) {
        a[j] += __shfl_xor(a[j], 8, 64);
        a[j] += __shfl_xor(a[j], 16, 64);
        a[j] += __shfl_xor(a[j], 32, 64);
    }
    if (eg == 0) {
        float inv = (lsum > 0.f) ? 1.f / lsum : 0.f;
        float o[8];
#pragma unroll
        for (int j = 0; j < 8; ++j) o[j] = a[j] * inv + b2f(b2[d8 * 8 + j]);
        size_t ob = ((size_t)node << 6) + d8 * 8;
        if (isbf) {
            u16x8 r;
#pragma unroll
            for (int j = 0; j < 8; ++j) r[j] = f2b(o[j]);
            *(u16x8*)&((unsigned short*)out)[ob] = r;
        } else {
            float4 r0, r1;
            r0.x = o[0]; r0.y = o[1]; r0.z = o[2]; r0.w = o[3];
            r1.x = o[4]; r1.y = o[5]; r1.z = o[6]; r1.w = o[7];
            *(float4*)&((float*)out)[ob] = r0;
            *(float4*)&((float*)out)[ob + 4] = r1;
        }
    }
}

extern "C" void kernel_launch(void* const* d_in, const int* in_sizes, int n_in,
                              void* d_out, int out_size, void* d_ws, size_t ws_size,
                              hipStream_t stream) {
    const void* h   = d_in[0];
    const int*  src = (const int*)d_in[1];
    const int*  dst = (const int*)d_in[2];
    const void* W1  = d_in[3];
    const void* al1 = d_in[4];
    const void* ar1 = d_in[5];
    const void* b1  = d_in[6];
    const void* W2  = d_in[7];
    const void* al2 = d_in[8];
    const void* ar2 = d_in[9];
    const void* b2  = d_in[10];

    char* w = (char*)d_ws;
    size_t off = 0;
    auto alloc = [&](size_t bytes) -> void* {
        void* p = w + off;
        off = (off + bytes + 255) & ~(size_t)255;
        return p;
    };
    int* flag               = (int*)alloc(8);
    int* cnt                = (int*)alloc(NN * 4);
    int* bucket             = (int*)alloc((size_t)NN * BCAP * 4);   // 5.12 MB
    unsigned short* canon   = (unsigned short*)alloc(960 * 2);
    unsigned short* W1T     = (unsigned short*)alloc(256 * 256 * 2);
    unsigned short* W2T     = (unsigned short*)alloc(64 * 256 * 2);
    unsigned short* feat1   = (unsigned short*)alloc((size_t)NN * 256 * 2);
    float* el1t             = (float*)alloc((size_t)NH * ELP * 4);  // head-major el, 160KB
    float* er1              = (float*)alloc(NN * NH * 4);
    unsigned short* h1      = (unsigned short*)alloc((size_t)NN * 256 * 2);
    unsigned short* feat2   = (unsigned short*)alloc((size_t)NN * 64 * 2);
    float* el2              = (float*)alloc(NN * 4);
    float* er2              = (float*)alloc(NN * 4);
    (void)ws_size; (void)in_sizes; (void)n_in; (void)out_size;

    unsigned short* cal1 = canon + 0;
    unsigned short* car1 = canon + 256;
    unsigned short* cb1  = canon + 512;
    unsigned short* cal2 = canon + 768;
    unsigned short* car2 = canon + 832;
    unsigned short* cb2  = canon + 896;

    // 1: prep (flag + canon + transposes + cnt zero)
    k_prep<<<363, 256, 0, stream>>>((const unsigned short*)h, W1, W2,
                                    al1, ar1, b1, al2, ar2, b2,
                                    W1T, W2T, canon, cnt, flag);
    // 2: layer-1 GEMM (64-row tiles; head-major el1t) + bucket CSR build
    k_g1b<<<GEMM1_BLOCKS + BUILD_BLOCKS, 256, 0, stream>>>(h, W1T, feat1, el1t, er1,
                                                           cal1, car1, flag,
                                                           src, dst, cnt, bucket);
    // 3: layer-1 edge aggregate, head-sliced (L2-resident feat slab + L1-resident el slab)
    k_e1h<<<NN, 256, 0, stream>>>(cnt, bucket, el1t, er1, feat1, cb1, h1);
    // 4: layer-2 GEMM (h1 known bf16)
    k_gemm<<<dim3(GEMM1_MT, 1), 256, 0, stream>>>(h1, W2T, feat2, el2, er2,
                                                  cal2, car2, NN, 64, 1);
    // 5: layer-2 edge aggregate -> output
    k_edge2<<<(NN + 3) / 4, 256, 0, stream>>>(cnt, bucket, el2, er2, feat2, cb2, d_out, flag);
}